// Round 15
// baseline (96.172 us; speedup 1.0000x reference)
//
#include <hip/hip_runtime.h>

// 3-NN IDW upsampling, round 15: round 14 with the staging-layout bug fixed.
// r14 FAILED because ssrt.w carried the original index while the dot-form
// distance needed |p|^2 in .w. Now: ssrt = {x,y,z,|p|^2}; original index
// lives in a separate ws array, staged to LDS as u16 (r7/r8-proven pattern).
// Everything else identical to r14: x-bucket sort, phase-A theta bound,
// bucket-granular window superset, dense 4-lane-split window scan with
// top-4 truncated keys/lane (r10-proven retention), 16-candidate exact-f64
// re-rank + f64 IDW epilogue (absmax 0.00390625 in all passing rounds).

constexpr int      B     = 2;
constexpr int      S     = 4096;
constexpr int      NQ    = 16384;
constexpr int      NBIN  = 256;
constexpr float    XLO   = -4.25f;
constexpr float    XINV  = 256.0f / 8.5f;
constexpr unsigned NOKEY = 0xFFFFFFFFu;

// workspace offsets (bytes); total ~297 KB (r5 used 459 KB successfully)
constexpr size_t OFF_DSRT = 0;         // u32[2][16384]   = 128 KB
constexpr size_t OFF_SSRT = 131072;    // float4[2][4096] = 128 KB
constexpr size_t OFF_SPFX = 262144;    // u32[2][257]     = 2056 B
constexpr size_t OFF_SIDX = 264704;    // u32[2][4096]    = 32 KB

__device__ __forceinline__ unsigned med3u(unsigned a, unsigned b, unsigned c) {
    unsigned d;
    asm("v_med3_u32 %0, %1, %2, %3" : "=v"(d) : "v"(a), "v"(b), "v"(c));
    return d;
}
__device__ __forceinline__ float med3f(float a, float b, float c) {
    float d;
    asm("v_med3_f32 %0, %1, %2, %3" : "=v"(d) : "v"(a), "v"(b), "v"(c));
    return d;
}
__device__ __forceinline__ int xbin(float v) {
    int c = (int)floorf((v - XLO) * XINV);
    return min(max(c, 0), NBIN - 1);
}

// ---------------- bucket-sort points + queries by x-bin --------------------
__global__ __launch_bounds__(1024)
void k_sort(const float* __restrict__ xyz, const float* __restrict__ sxyz,
            unsigned* __restrict__ ws32)
{
    __shared__ unsigned cnt[NBIN];
    __shared__ unsigned cur[NBIN];
    __shared__ unsigned wt[4];
    const int  a   = blockIdx.x;       // 0,1: points b; 2,3: queries b
    const int  b   = a & 1;
    const bool pts = a < 2;
    const int  n   = pts ? S : NQ;
    const float* xb = (pts ? sxyz : xyz) + (size_t)b * 3 * n;
    const int t = threadIdx.x, lane = t & 63, w = t >> 6;

    if (t < NBIN) cnt[t] = 0u;
    __syncthreads();
    for (int i = t; i < n; i += 1024) atomicAdd(&cnt[xbin(xb[i])], 1u);
    __syncthreads();

    unsigned c = 0, sc = 0;
    if (t < NBIN) {
        c = cnt[t]; sc = c;
        #pragma unroll
        for (int d = 1; d < 64; d <<= 1) {
            const unsigned o = __shfl_up(sc, d, 64);
            if (lane >= d) sc += o;
        }
        if (lane == 63) wt[w] = sc;
    }
    __syncthreads();
    if (t < NBIN) {
        unsigned wb = 0;
        #pragma unroll
        for (int k = 0; k < 4; ++k) wb += (k < w) ? wt[k] : 0u;
        const unsigned excl = wb + sc - c;
        cur[t] = excl;
        if (pts) {
            ws32[OFF_SPFX / 4 + b * 257 + t] = excl;
            if (t == NBIN - 1) ws32[OFF_SPFX / 4 + b * 257 + NBIN] = excl + c;  // = S
        }
    }
    __syncthreads();

    if (pts) {
        float4*   ssrt  = reinterpret_cast<float4*>((char*)ws32 + OFF_SSRT) + b * S;
        unsigned* sidxg = ws32 + OFF_SIDX / 4 + b * S;
        const float* yb = xb + n;
        const float* zb = xb + 2 * n;
        for (int i = t; i < n; i += 1024) {
            const float x = xb[i], y = yb[i], z = zb[i];
            const float pp = fmaf(z, z, fmaf(y, y, x * x));
            const unsigned pos = atomicAdd(&cur[xbin(x)], 1u);
            ssrt[pos]  = make_float4(x, y, z, pp);     // .w = |p|^2 (r14 bug fix)
            sidxg[pos] = (unsigned)i;                  // orig idx separate
        }
    } else {
        unsigned* dsrt = ws32 + OFF_DSRT / 4 + b * NQ;
        for (int i = t; i < n; i += 1024) {
            const unsigned pos = atomicAdd(&cur[xbin(xb[i])], 1u);
            dsrt[pos] = (unsigned)i;
        }
    }
}

// ---------------- main: windowed dense scan + f64 epilogue -----------------
__global__ __launch_bounds__(256, 2)
void k_knn(const float* __restrict__ xyz, const float* __restrict__ sflow,
           float* __restrict__ out, const unsigned* __restrict__ ws32)
{
    __shared__ float4 pq[S];                    // 64 KiB x-sorted {x,y,z,|p|^2}
    __shared__ unsigned short sidx[S];          // 8 KiB sorted -> orig index
    __shared__ unsigned short pfx16[NBIN + 2];  // bin prefix

    const int t = threadIdx.x, lane = t & 63, wv = t >> 6;
    const int chk = blockIdx.x;                 // 0..255
    const int b   = blockIdx.y;

    const float4*   ssrt  = reinterpret_cast<const float4*>((const char*)ws32 + OFF_SSRT) + b * S;
    const unsigned* sidxg = ws32 + OFF_SIDX / 4 + b * S;
    const unsigned* spfx  = ws32 + OFF_SPFX / 4 + b * 257;
    const unsigned* dsrt  = ws32 + OFF_DSRT / 4 + b * NQ;

    for (int i = t; i < S; i += 256) {
        pq[i]   = ssrt[i];
        sidx[i] = (unsigned short)sidxg[i];
    }
    for (int i = t; i < NBIN + 1; i += 256) pfx16[i] = (unsigned short)spfx[i];
    __syncthreads();

    const int qn  = lane & 15;                  // query within wave
    const int par = lane >> 4;                  // 4-way point split
    // load balance: each wave of a block takes queries from a different
    // x-quartile; a wave's 16 queries stay rank-consecutive (x-adjacent).
    const int qslot = wv * (NQ / 4) + chk * 16 + qn;
    const unsigned qi = dsrt[qslot];

    const float* xb = xyz + (size_t)b * 3 * NQ;
    const float qx = xb[qi], qy = xb[NQ + qi], qz = xb[2 * NQ + qi];
    const float m2x = -2.0f * qx, m2y = -2.0f * qy, m2z = -2.0f * qz;
    const float qqc = fmaf(qz, qz, fmaf(qy, qy, qx * qx)) + 1e-3f;

    // ---- phase A: 256-point rank chunk -> theta (upper bound on d3+bias) --
    const float q0x = __shfl(qx, 0, 64);
    const int   cb  = xbin(q0x);
    const int   c0  = min(max((int)pfx16[cb] - 128, 0), S - 256);
    float m0 = 1e30f, m1 = 1e30f, m2v = 1e30f;
    for (int i = 0; i < 64; ++i) {
        const float4 p = pq[c0 + 4 * i + par];
        const float v  = fmaf(m2x, p.x, fmaf(m2y, p.y, fmaf(m2z, p.z, qqc)));
        const float v2 = v + p.w;               // d2 + 1e-3 (fp32)
        m2v = med3f(m1, m2v, v2);
        m1  = med3f(m0, m1, v2);
        m0  = fminf(m0, v2);
    }
    float th = fminf(m2v, __shfl_xor(m2v, 16, 64));
    th = fminf(th, __shfl_xor(th, 32, 64));     // quad-min of subset 3rd-bests

    // ---- window: bucket-granular superset of |x_p - x_q| <= sqrt(theta) ---
    const float sq  = sqrtf(th) * 1.001f + 1e-3f;
    const int   blo = xbin(qx - sq), bhi = xbin(qx + sq);
    const int   wlo = (int)pfx16[blo], whi = (int)pfx16[bhi + 1];
    int tm = (whi - wlo + 3) >> 2;
    #pragma unroll
    for (int d = 1; d < 64; d <<= 1) tm = max(tm, __shfl_xor(tm, d, 64));

    // ---- phase B: dense window scan, disjoint j mod 4 per lane ------------
    unsigned k0 = NOKEY, k1 = NOKEY, k2 = NOKEY, k3 = NOKEY;
    for (int i = 0; i < tm; ++i) {
        const int j  = wlo + 4 * i + par;
        const int jc = min(j, S - 1);
        const float4 p = pq[jc];
        const float v  = fmaf(m2x, p.x, fmaf(m2y, p.y, fmaf(m2z, p.z, qqc)));
        const float v2 = v + p.w;
        unsigned key = (__float_as_uint(v2) & 0xFFFFF000u) | (unsigned)jc;
        key = (j < whi) ? key : NOKEY;
        k3 = med3u(k2, k3, key);
        k2 = med3u(k1, k2, key);
        k1 = med3u(k0, k1, key);
        k0 = min(k0, key);
    }

    // ---- gather the quad's 16 candidate keys -------------------------------
    const unsigned a0 = (unsigned)__shfl_xor((int)k0, 16, 64);
    const unsigned a1 = (unsigned)__shfl_xor((int)k1, 16, 64);
    const unsigned a2 = (unsigned)__shfl_xor((int)k2, 16, 64);
    const unsigned a3 = (unsigned)__shfl_xor((int)k3, 16, 64);
    const unsigned b0 = (unsigned)__shfl_xor((int)k0, 32, 64);
    const unsigned b1 = (unsigned)__shfl_xor((int)k1, 32, 64);
    const unsigned b2 = (unsigned)__shfl_xor((int)k2, 32, 64);
    const unsigned b3 = (unsigned)__shfl_xor((int)k3, 32, 64);
    const unsigned c0k = (unsigned)__shfl_xor((int)k0, 48, 64);
    const unsigned c1k = (unsigned)__shfl_xor((int)k1, 48, 64);
    const unsigned c2k = (unsigned)__shfl_xor((int)k2, 48, 64);
    const unsigned c3k = (unsigned)__shfl_xor((int)k3, 48, 64);

    // ---- epilogue (par==0): exact-f64 re-rank of 16 + f64 IDW (r10 shape) --
    if (par == 0) {
        const unsigned bkarr[16] = { k0, k1, k2, k3, a0, a1, a2, a3,
                                     b0, b1, b2, b3, c0k, c1k, c2k, c3k };
        const double qxd = (double)qx, qyd = (double)qy, qzd = (double)qz;
        double e0 = 1e300, e1 = 1e300, e2 = 1e300;
        int    i0 = 0,     i1 = 0,     i2 = 0;
        #pragma unroll
        for (int c = 0; c < 16; ++c) {
            const unsigned key = bkarr[c];
            if (key == NOKEY) continue;
            const int j = (int)(key & 0xFFFu);
            const float4 p = pq[j];
            const double dx = qxd - (double)p.x;
            const double dy = qyd - (double)p.y;
            const double dz = qzd - (double)p.z;
            const double d2 = dx * dx + dy * dy + dz * dz;
            if (d2 < e2) {
                if (d2 < e1) {
                    e2 = e1; i2 = i1;
                    if (d2 < e0) { e1 = e0; i1 = i0; e0 = d2; i0 = j; }
                    else         { e1 = d2; i1 = j; }
                } else {
                    e2 = d2; i2 = j;
                }
            }
        }

        double dist0 = sqrt(e0); dist0 = dist0 > 1e-10 ? dist0 : 1e-10;
        double dist1 = sqrt(e1); dist1 = dist1 > 1e-10 ? dist1 : 1e-10;
        double dist2 = sqrt(e2); dist2 = dist2 > 1e-10 ? dist2 : 1e-10;
        const double inv0 = 1.0 / dist0;
        const double inv1 = 1.0 / dist1;
        const double inv2 = 1.0 / dist2;
        const double wsum = inv0 + inv1 + inv2;

        const int so0 = (int)sidx[i0];
        const int so1 = (int)sidx[i1];
        const int so2 = (int)sidx[i2];

        const float* fb = sflow + (size_t)b * 3 * S;
        float*       ob = out   + (size_t)b * 3 * NQ;
        #pragma unroll
        for (int c = 0; c < 3; ++c) {
            const float* fc = fb + c * S;
            const double o =
                (inv0 * (double)fc[so0] +
                 inv1 * (double)fc[so1] +
                 inv2 * (double)fc[so2]) / wsum;
            ob[c * NQ + qi] = (float)o;
        }
    }
}

extern "C" void kernel_launch(void* const* d_in, const int* in_sizes, int n_in,
                              void* d_out, int out_size, void* d_ws, size_t ws_size,
                              hipStream_t stream)
{
    const float* xyz  = (const float*)d_in[0];
    const float* sxyz = (const float*)d_in[1];
    const float* sflw = (const float*)d_in[2];
    float*       out  = (float*)d_out;
    unsigned*    ws32 = (unsigned*)d_ws;      // needs ~297 KB

    k_sort<<<4, 1024, 0, stream>>>(xyz, sxyz, ws32);
    k_knn<<<dim3(NQ / 64, B), 256, 0, stream>>>(xyz, sflw, out, ws32);
}

// Round 16
// 88.811 us; speedup vs baseline: 1.0829x; 1.0829x over previous
//
#include <hip/hip_runtime.h>

// 3-NN IDW upsampling, round 16: r15 windowed scan, execution-repaired.
//  (a) queries sorted by (yz-radius class, xbin): wave's 16 queries have
//      homogeneous window sizes -> wave-max ~ mean (kills r15's 4x padding).
//  (b) wave-UNION window: all lanes share one [U0,U1) -> broadcast LDS reads
//      (8 consecutive float4/iter, conflict-free), uniform trip count.
//  (c) dual med3 chains per lane (even/odd, merged by sorted inserts) = 2x ILP.
// Phase-A theta bound, bucket-granular superset window, top-4/lane retention,
// quad gather, exact-f64 re-rank + f64 IDW epilogue: verbatim r15 (passed,
// absmax 0.00390625).

constexpr int      B     = 2;
constexpr int      S     = 4096;
constexpr int      NQ    = 16384;
constexpr int      NBIN  = 256;
constexpr int      NBQ   = 1024;      // query buckets = 4 classes x 256 xbins
constexpr float    XLO   = -4.25f;
constexpr float    XINV  = 256.0f / 8.5f;
constexpr unsigned NOKEY = 0xFFFFFFFFu;

// workspace offsets (bytes); total ~297 KB
constexpr size_t OFF_DSRT = 0;         // u32[2][16384]   = 128 KB
constexpr size_t OFF_SSRT = 131072;    // float4[2][4096] = 128 KB
constexpr size_t OFF_SPFX = 262144;    // u32[2][257]
constexpr size_t OFF_SIDX = 264704;    // u32[2][4096]    = 32 KB

__device__ __forceinline__ unsigned med3u(unsigned a, unsigned b, unsigned c) {
    unsigned d;
    asm("v_med3_u32 %0, %1, %2, %3" : "=v"(d) : "v"(a), "v"(b), "v"(c));
    return d;
}
__device__ __forceinline__ float med3f(float a, float b, float c) {
    float d;
    asm("v_med3_f32 %0, %1, %2, %3" : "=v"(d) : "v"(a), "v"(b), "v"(c));
    return d;
}
__device__ __forceinline__ int xbin(float v) {
    int c = (int)floorf((v - XLO) * XINV);
    return min(max(c, 0), NBIN - 1);
}

// ---------------- bucket-sort: points by xbin; queries by (class, xbin) ----
__global__ __launch_bounds__(1024)
void k_sort(const float* __restrict__ xyz, const float* __restrict__ sxyz,
            unsigned* __restrict__ ws32)
{
    __shared__ unsigned cnt[NBQ];
    __shared__ unsigned cur[NBQ];
    __shared__ unsigned wt[16];
    const int  a   = blockIdx.x;       // 0,1: points b; 2,3: queries b
    const int  b   = a & 1;
    const bool pts = a < 2;
    const int  n   = pts ? S : NQ;
    const float* xb = (pts ? sxyz : xyz) + (size_t)b * 3 * n;
    const float* yb = xb + n;
    const float* zb = xb + 2 * n;
    const int t = threadIdx.x, lane = t & 63, w = t >> 6;

    cnt[t] = 0u;
    __syncthreads();
    for (int i = t; i < n; i += 1024) {
        int key;
        if (pts) {
            key = xbin(xb[i]);
        } else {
            const float y = yb[i], z = zb[i];
            const float r2 = fmaf(y, y, z * z);
            const int cls = (r2 < 2.f) ? 0 : (r2 < 4.f) ? 1 : (r2 < 7.f) ? 2 : 3;
            key = cls * NBIN + xbin(xb[i]);
        }
        atomicAdd(&cnt[key], 1u);
    }
    __syncthreads();

    // exclusive scan over 1024 buckets, one per thread (r8-proven shape)
    const unsigned c = cnt[t];
    unsigned sc = c;
    #pragma unroll
    for (int d = 1; d < 64; d <<= 1) {
        const unsigned o = __shfl_up(sc, d, 64);
        if (lane >= d) sc += o;
    }
    if (lane == 63) wt[w] = sc;
    __syncthreads();
    unsigned wb = 0;
    #pragma unroll
    for (int k = 0; k < 16; ++k) wb += (k < w) ? wt[k] : 0u;
    const unsigned excl = wb + sc - c;
    cur[t] = excl;
    if (pts && t <= NBIN)                       // t=256's excl == S
        ws32[OFF_SPFX / 4 + b * 257 + t] = excl;
    __syncthreads();

    if (pts) {
        float4*   ssrt  = reinterpret_cast<float4*>((char*)ws32 + OFF_SSRT) + b * S;
        unsigned* sidxg = ws32 + OFF_SIDX / 4 + b * S;
        for (int i = t; i < n; i += 1024) {
            const float x = xb[i], y = yb[i], z = zb[i];
            const float pp = fmaf(z, z, fmaf(y, y, x * x));
            const unsigned pos = atomicAdd(&cur[xbin(x)], 1u);
            ssrt[pos]  = make_float4(x, y, z, pp);
            sidxg[pos] = (unsigned)i;
        }
    } else {
        unsigned* dsrt = ws32 + OFF_DSRT / 4 + b * NQ;
        for (int i = t; i < n; i += 1024) {
            const float y = yb[i], z = zb[i];
            const float r2 = fmaf(y, y, z * z);
            const int cls = (r2 < 2.f) ? 0 : (r2 < 4.f) ? 1 : (r2 < 7.f) ? 2 : 3;
            const int key = cls * NBIN + xbin(xb[i]);
            const unsigned pos = atomicAdd(&cur[key], 1u);
            dsrt[pos] = (unsigned)i;
        }
    }
}

// ---------------- main: union-window broadcast scan + f64 epilogue ---------
__global__ __launch_bounds__(256, 2)
void k_knn(const float* __restrict__ xyz, const float* __restrict__ sflow,
           float* __restrict__ out, const unsigned* __restrict__ ws32)
{
    __shared__ float4 pq[S];                    // 64 KiB x-sorted {x,y,z,|p|^2}
    __shared__ unsigned short sidx[S];          // 8 KiB sorted -> orig index
    __shared__ unsigned short pfx16[NBIN + 2];  // bin prefix

    const int t = threadIdx.x, lane = t & 63, wv = t >> 6;
    const int chk = blockIdx.x;                 // 0..255
    const int b   = blockIdx.y;

    const float4*   ssrt  = reinterpret_cast<const float4*>((const char*)ws32 + OFF_SSRT) + b * S;
    const unsigned* sidxg = ws32 + OFF_SIDX / 4 + b * S;
    const unsigned* spfx  = ws32 + OFF_SPFX / 4 + b * 257;
    const unsigned* dsrt  = ws32 + OFF_DSRT / 4 + b * NQ;

    for (int i = t; i < S; i += 256) {
        pq[i]   = ssrt[i];
        sidx[i] = (unsigned short)sidxg[i];
    }
    for (int i = t; i < NBIN + 1; i += 256) pfx16[i] = (unsigned short)spfx[i];
    __syncthreads();

    const int qn  = lane & 15;                  // query within wave
    const int par = lane >> 4;                  // 4-way point split
    const int qslot = wv * (NQ / 4) + chk * 16 + qn;
    const unsigned qi = dsrt[qslot];

    const float* xb = xyz + (size_t)b * 3 * NQ;
    const float qx = xb[qi], qy = xb[NQ + qi], qz = xb[2 * NQ + qi];
    const float m2x = -2.0f * qx, m2y = -2.0f * qy, m2z = -2.0f * qz;
    const float qqc = fmaf(qz, qz, fmaf(qy, qy, qx * qx)) + 1e-3f;

    // ---- phase A: 256-point rank chunk -> theta (r15-proven bound) --------
    const float q0x = __shfl(qx, 0, 64);
    const int   cb  = xbin(q0x);
    const int   c0  = min(max((int)pfx16[cb] - 128, 0), S - 256);
    float m0 = 1e30f, m1 = 1e30f, m2v = 1e30f;
    for (int i = 0; i < 64; ++i) {
        const float4 p = pq[c0 + 4 * i + par];
        const float v  = fmaf(m2x, p.x, fmaf(m2y, p.y, fmaf(m2z, p.z, qqc)));
        const float v2 = v + p.w;
        m2v = med3f(m1, m2v, v2);
        m1  = med3f(m0, m1, v2);
        m0  = fminf(m0, v2);
    }
    float th = fminf(m2v, __shfl_xor(m2v, 16, 64));
    th = fminf(th, __shfl_xor(th, 32, 64));     // quad-min of subset 3rd-bests

    // ---- per-query window, then wave-union (bucket-granular superset) -----
    const float sq  = sqrtf(th) * 1.001f + 1e-3f;
    const int   blo = xbin(qx - sq), bhi = xbin(qx + sq);
    int U0 = (int)pfx16[blo], U1 = (int)pfx16[bhi + 1];
    #pragma unroll
    for (int d = 1; d < 64; d <<= 1) {
        U0 = min(U0, __shfl_xor(U0, d, 64));
        U1 = max(U1, __shfl_xor(U1, d, 64));
    }

    // ---- dual-chain union scan: broadcast reads, top-4 per chain ----------
    unsigned cA0 = NOKEY, cA1 = NOKEY, cA2 = NOKEY, cA3 = NOKEY;
    unsigned cB0 = NOKEY, cB1 = NOKEY, cB2 = NOKEY, cB3 = NOKEY;
    const int iters = (U1 - U0 + 7) >> 3;
    for (int k = 0; k < iters; ++k) {
        const int jA = U0 + (k << 3) + par;
        const int jB = jA + 4;
        const float4 pA = pq[min(jA, S - 1)];
        const float4 pB = pq[min(jB, S - 1)];
        {
            const float v  = fmaf(m2x, pA.x, fmaf(m2y, pA.y, fmaf(m2z, pA.z, qqc)));
            const float v2 = v + pA.w;
            unsigned key = (__float_as_uint(v2) & 0xFFFFF000u) | (unsigned)min(jA, S - 1);
            key = (jA < U1) ? key : NOKEY;
            cA3 = med3u(cA2, cA3, key);
            cA2 = med3u(cA1, cA2, key);
            cA1 = med3u(cA0, cA1, key);
            cA0 = min(cA0, key);
        }
        {
            const float v  = fmaf(m2x, pB.x, fmaf(m2y, pB.y, fmaf(m2z, pB.z, qqc)));
            const float v2 = v + pB.w;
            unsigned key = (__float_as_uint(v2) & 0xFFFFF000u) | (unsigned)min(jB, S - 1);
            key = (jB < U1) ? key : NOKEY;
            cB3 = med3u(cB2, cB3, key);
            cB2 = med3u(cB1, cB2, key);
            cB1 = med3u(cB0, cB1, key);
            cB0 = min(cB0, key);
        }
    }
    // merge chain B into A -> exact top-4 of this lane's stripe
    {
        unsigned kk;
        kk = cB0; cA3 = med3u(cA2, cA3, kk); cA2 = med3u(cA1, cA2, kk); cA1 = med3u(cA0, cA1, kk); cA0 = min(cA0, kk);
        kk = cB1; cA3 = med3u(cA2, cA3, kk); cA2 = med3u(cA1, cA2, kk); cA1 = med3u(cA0, cA1, kk); cA0 = min(cA0, kk);
        kk = cB2; cA3 = med3u(cA2, cA3, kk); cA2 = med3u(cA1, cA2, kk); cA1 = med3u(cA0, cA1, kk); cA0 = min(cA0, kk);
        kk = cB3; cA3 = med3u(cA2, cA3, kk); cA2 = med3u(cA1, cA2, kk); cA1 = med3u(cA0, cA1, kk); cA0 = min(cA0, kk);
    }

    // ---- gather the quad's 16 candidate keys (r15 verbatim) ---------------
    const unsigned g10 = (unsigned)__shfl_xor((int)cA0, 16, 64);
    const unsigned g11 = (unsigned)__shfl_xor((int)cA1, 16, 64);
    const unsigned g12 = (unsigned)__shfl_xor((int)cA2, 16, 64);
    const unsigned g13 = (unsigned)__shfl_xor((int)cA3, 16, 64);
    const unsigned g20 = (unsigned)__shfl_xor((int)cA0, 32, 64);
    const unsigned g21 = (unsigned)__shfl_xor((int)cA1, 32, 64);
    const unsigned g22 = (unsigned)__shfl_xor((int)cA2, 32, 64);
    const unsigned g23 = (unsigned)__shfl_xor((int)cA3, 32, 64);
    const unsigned g30 = (unsigned)__shfl_xor((int)cA0, 48, 64);
    const unsigned g31 = (unsigned)__shfl_xor((int)cA1, 48, 64);
    const unsigned g32 = (unsigned)__shfl_xor((int)cA2, 48, 64);
    const unsigned g33 = (unsigned)__shfl_xor((int)cA3, 48, 64);

    // ---- epilogue (par==0): exact-f64 re-rank of 16 + f64 IDW (r15) -------
    if (par == 0) {
        const unsigned bkarr[16] = { cA0, cA1, cA2, cA3, g10, g11, g12, g13,
                                     g20, g21, g22, g23, g30, g31, g32, g33 };
        const double qxd = (double)qx, qyd = (double)qy, qzd = (double)qz;
        double e0 = 1e300, e1 = 1e300, e2 = 1e300;
        int    i0 = 0,     i1 = 0,     i2 = 0;
        #pragma unroll
        for (int c = 0; c < 16; ++c) {
            const unsigned key = bkarr[c];
            if (key == NOKEY) continue;
            const int j = (int)(key & 0xFFFu);
            const float4 p = pq[j];
            const double dx = qxd - (double)p.x;
            const double dy = qyd - (double)p.y;
            const double dz = qzd - (double)p.z;
            const double d2 = dx * dx + dy * dy + dz * dz;
            if (d2 < e2) {
                if (d2 < e1) {
                    e2 = e1; i2 = i1;
                    if (d2 < e0) { e1 = e0; i1 = i0; e0 = d2; i0 = j; }
                    else         { e1 = d2; i1 = j; }
                } else {
                    e2 = d2; i2 = j;
                }
            }
        }

        double dist0 = sqrt(e0); dist0 = dist0 > 1e-10 ? dist0 : 1e-10;
        double dist1 = sqrt(e1); dist1 = dist1 > 1e-10 ? dist1 : 1e-10;
        double dist2 = sqrt(e2); dist2 = dist2 > 1e-10 ? dist2 : 1e-10;
        const double inv0 = 1.0 / dist0;
        const double inv1 = 1.0 / dist1;
        const double inv2 = 1.0 / dist2;
        const double wsum = inv0 + inv1 + inv2;

        const int so0 = (int)sidx[i0];
        const int so1 = (int)sidx[i1];
        const int so2 = (int)sidx[i2];

        const float* fb = sflow + (size_t)b * 3 * S;
        float*       ob = out   + (size_t)b * 3 * NQ;
        #pragma unroll
        for (int c = 0; c < 3; ++c) {
            const float* fc = fb + c * S;
            const double o =
                (inv0 * (double)fc[so0] +
                 inv1 * (double)fc[so1] +
                 inv2 * (double)fc[so2]) / wsum;
            ob[c * NQ + qi] = (float)o;
        }
    }
}

extern "C" void kernel_launch(void* const* d_in, const int* in_sizes, int n_in,
                              void* d_out, int out_size, void* d_ws, size_t ws_size,
                              hipStream_t stream)
{
    const float* xyz  = (const float*)d_in[0];
    const float* sxyz = (const float*)d_in[1];
    const float* sflw = (const float*)d_in[2];
    float*       out  = (float*)d_out;
    unsigned*    ws32 = (unsigned*)d_ws;      // needs ~297 KB

    k_sort<<<4, 1024, 0, stream>>>(xyz, sxyz, ws32);
    k_knn<<<dim3(NQ / 64, B), 256, 0, stream>>>(xyz, sflw, out, ws32);
}

// Round 17
// 62.283 us; speedup vs baseline: 1.5441x; 1.4259x over previous
//
#include <hip/hip_runtime.h>

// 3-NN IDW upsampling, round 17: r13's proven execution shape (wave = 4
// shared queries x 64-lane point split, dense conflict-free b128 scan)
// applied to an x-sorted WINDOW instead of all 4096 points.
// k_sort: r15-proven bucket sort (points + queries by 256 uniform x-bins).
// k_knn: per wave: phase A = 256-pt rank chunk -> theta_q (butterfly-min of
//   per-lane 3rd-best v2; valid d3 upper bound, r15/16-proven); window =
//   bucket-granular superset, union over the wave's 4 x-adjacent queries;
//   phase B = r13 inner loop over [U0,U1) with 64-lane stride; per-query
//   top-3 keys/lane -> r13 merge (16x top-4-of-12 -> top-8) -> exact-f64
//   re-rank (global ssrt/sidxg, L2-hot) + f64 IDW. absmax 0.00390625.

constexpr int      B     = 2;
constexpr int      S     = 4096;
constexpr int      NQ    = 16384;
constexpr int      NBIN  = 256;
constexpr float    XLO   = -4.25f;
constexpr float    XINV  = 256.0f / 8.5f;
constexpr unsigned NOKEY = 0xFFFFFFFFu;

constexpr int THREADS = 512;          // 8 waves
constexpr int Q       = 4;            // queries per wave
constexpr int PPB     = 32;           // queries per block (8 waves x 4)
constexpr int K       = 3;            // per-lane top-K kept
constexpr int KA      = 4;            // stage-A top-K per 12-key chunk
constexpr int KM      = 8;            // final candidates for f64 re-rank
constexpr int KROW    = 64 * K + 5;   // 197 dwords (odd: breaks bank stride)
constexpr int KB2     = PPB * KROW;   // 6304 dwords

// workspace offsets (bytes)
constexpr size_t OFF_DSRT = 0;        // u32[2][16384]
constexpr size_t OFF_SSRT = 131072;   // float4[2][4096]
constexpr size_t OFF_SPFX = 262144;   // u32[2][257]
constexpr size_t OFF_SIDX = 264704;   // u32[2][4096]

__device__ __forceinline__ unsigned med3u(unsigned a, unsigned b, unsigned c) {
    unsigned d;
    asm("v_med3_u32 %0, %1, %2, %3" : "=v"(d) : "v"(a), "v"(b), "v"(c));
    return d;
}
__device__ __forceinline__ float med3f(float a, float b, float c) {
    float d;
    asm("v_med3_f32 %0, %1, %2, %3" : "=v"(d) : "v"(a), "v"(b), "v"(c));
    return d;
}
__device__ __forceinline__ int xbin(float v) {
    int c = (int)floorf((v - XLO) * XINV);
    return min(max(c, 0), NBIN - 1);
}

// ---------------- bucket-sort points + queries by x-bin (r15 verbatim) -----
__global__ __launch_bounds__(1024)
void k_sort(const float* __restrict__ xyz, const float* __restrict__ sxyz,
            unsigned* __restrict__ ws32)
{
    __shared__ unsigned cnt[NBIN];
    __shared__ unsigned cur[NBIN];
    __shared__ unsigned wt[4];
    const int  a   = blockIdx.x;       // 0,1: points b; 2,3: queries b
    const int  b   = a & 1;
    const bool pts = a < 2;
    const int  n   = pts ? S : NQ;
    const float* xb = (pts ? sxyz : xyz) + (size_t)b * 3 * n;
    const int t = threadIdx.x, lane = t & 63, w = t >> 6;

    if (t < NBIN) cnt[t] = 0u;
    __syncthreads();
    for (int i = t; i < n; i += 1024) atomicAdd(&cnt[xbin(xb[i])], 1u);
    __syncthreads();

    unsigned c = 0, sc = 0;
    if (t < NBIN) {
        c = cnt[t]; sc = c;
        #pragma unroll
        for (int d = 1; d < 64; d <<= 1) {
            const unsigned o = __shfl_up(sc, d, 64);
            if (lane >= d) sc += o;
        }
        if (lane == 63) wt[w] = sc;
    }
    __syncthreads();
    if (t < NBIN) {
        unsigned wb = 0;
        #pragma unroll
        for (int k = 0; k < 4; ++k) wb += (k < w) ? wt[k] : 0u;
        const unsigned excl = wb + sc - c;
        cur[t] = excl;
        if (pts) {
            ws32[OFF_SPFX / 4 + b * 257 + t] = excl;
            if (t == NBIN - 1) ws32[OFF_SPFX / 4 + b * 257 + NBIN] = excl + c;
        }
    }
    __syncthreads();

    if (pts) {
        float4*   ssrt  = reinterpret_cast<float4*>((char*)ws32 + OFF_SSRT) + b * S;
        unsigned* sidxg = ws32 + OFF_SIDX / 4 + b * S;
        const float* yb = xb + n;
        const float* zb = xb + 2 * n;
        for (int i = t; i < n; i += 1024) {
            const float x = xb[i], y = yb[i], z = zb[i];
            const float pp = fmaf(z, z, fmaf(y, y, x * x));
            const unsigned pos = atomicAdd(&cur[xbin(x)], 1u);
            ssrt[pos]  = make_float4(x, y, z, pp);
            sidxg[pos] = (unsigned)i;
        }
    } else {
        unsigned* dsrt = ws32 + OFF_DSRT / 4 + b * NQ;
        for (int i = t; i < n; i += 1024) {
            const unsigned pos = atomicAdd(&cur[xbin(xb[i])], 1u);
            dsrt[pos] = (unsigned)i;
        }
    }
}

// ---------------- main: r13-shape windowed scan + f64 epilogue -------------
__global__ __launch_bounds__(THREADS, 4)
void k_knn(const float* __restrict__ xyz, const float* __restrict__ sflow,
           float* __restrict__ out, const unsigned* __restrict__ ws32)
{
    // 66.5 KiB: x-sorted {x,y,z,|p|^2} during scan; aliased as key-exchange
    // after (epilogue reads coords/idx from global ssrt/sidxg, L2-hot).
    __shared__ __align__(16) unsigned char smem_raw[(S + 32) * 16];
    float4*   pq   = reinterpret_cast<float4*>(smem_raw);
    unsigned* kbuf = reinterpret_cast<unsigned*>(smem_raw);
    __shared__ unsigned short pfx16[NBIN + 2];

    const int t   = threadIdx.x;
    const int s   = t & 63;              // lane = point split
    const int g   = t >> 6;              // wave = query group 0..7
    const int b   = blockIdx.y;
    const int chk = blockIdx.x;          // 0..511

    const float4*   ssrt  = reinterpret_cast<const float4*>((const char*)ws32 + OFF_SSRT) + b * S;
    const unsigned* sidxg = ws32 + OFF_SIDX / 4 + b * S;
    const unsigned* spfx  = ws32 + OFF_SPFX / 4 + b * 257;
    const unsigned* dsrt  = ws32 + OFF_DSRT / 4 + b * NQ;
    const float*    xb    = xyz + (size_t)b * 3 * NQ;

    for (int i = t; i < S; i += THREADS) pq[i] = ssrt[i];
    for (int i = t; i < NBIN + 1; i += THREADS) pfx16[i] = (unsigned short)spfx[i];

    // ---- the wave's 4 x-adjacent queries (shared by all 64 lanes) ----
    unsigned qid[Q];
    float qxs[Q], m2x[Q], m2y[Q], m2z[Q], qqc[Q];
    #pragma unroll
    for (int q = 0; q < Q; ++q) {
        qid[q] = dsrt[chk * PPB + g * Q + q];
        const float qx = xb[qid[q]];
        const float qy = xb[NQ + qid[q]];
        const float qz = xb[2 * NQ + qid[q]];
        qxs[q] = qx;
        m2x[q] = -2.0f * qx; m2y[q] = -2.0f * qy; m2z[q] = -2.0f * qz;
        qqc[q] = fmaf(qz, qz, fmaf(qy, qy, qx * qx)) + 1e-3f;
    }
    __syncthreads();

    // ---- phase A: 256-pt rank chunk -> theta_q (valid d3 upper bound) ----
    const int cb = xbin(qxs[1]);
    const int c0 = min(max((int)pfx16[cb] - 128, 0), S - 256);
    float A0[Q], A1[Q], A2[Q];
    #pragma unroll
    for (int q = 0; q < Q; ++q) { A0[q] = 1e30f; A1[q] = 1e30f; A2[q] = 1e30f; }
    #pragma unroll
    for (int i = 0; i < 4; ++i) {
        const float4 p = pq[c0 + (i << 6) + s];
        #pragma unroll
        for (int q = 0; q < Q; ++q) {
            const float v  = fmaf(m2x[q], p.x, fmaf(m2y[q], p.y, fmaf(m2z[q], p.z, qqc[q])));
            const float v2 = v + p.w;
            A2[q] = med3f(A1[q], A2[q], v2);
            A1[q] = med3f(A0[q], A1[q], v2);
            A0[q] = fminf(A0[q], v2);
        }
    }
    // butterfly min of per-lane 3rd-bests (>= true d3^2 + bias; proven)
    float th[Q];
    #pragma unroll
    for (int q = 0; q < Q; ++q) {
        float x = A2[q];
        #pragma unroll
        for (int d = 1; d < 64; d <<= 1) x = fminf(x, __shfl_xor(x, d, 64));
        th[q] = x;
    }

    // ---- wave-union window (bucket-granular superset; union of 4 only) ---
    int U0 = S, U1 = 0;
    #pragma unroll
    for (int q = 0; q < Q; ++q) {
        const float sq  = sqrtf(th[q]) * 1.0005f + 1e-3f;
        const int   blo = xbin(qxs[q] - sq), bhi = xbin(qxs[q] + sq);
        U0 = min(U0, (int)pfx16[blo]);
        U1 = max(U1, (int)pfx16[bhi + 1]);
    }

    // ---- phase B: r13 inner loop over the window, 64-lane stride ----------
    unsigned k0[Q], k1[Q], k2[Q];
    #pragma unroll
    for (int q = 0; q < Q; ++q) { k0[q] = NOKEY; k1[q] = NOKEY; k2[q] = NOKEY; }

    const int iters = (U1 - U0 + 63) >> 6;
    for (int i = 0; i < iters; ++i) {
        const int j  = U0 + (i << 6) + s;
        const int jc = min(j, S - 1);
        const float4 p = pq[jc];
        const bool ok = (j < U1);
        #pragma unroll
        for (int q = 0; q < Q; ++q) {
            const float v  = fmaf(m2x[q], p.x, fmaf(m2y[q], p.y, fmaf(m2z[q], p.z, qqc[q])));
            const float v2 = v + p.w;
            unsigned key = (__float_as_uint(v2) & 0xFFFFF000u) | (unsigned)jc;
            key = ok ? key : NOKEY;
            k2[q] = med3u(k1[q], k2[q], key);
            k1[q] = med3u(k0[q], k1[q], key);
            k0[q] = min(k0[q], key);
        }
    }

    // ---- publish per-lane sorted-3 lists (alias over pq; r13 verbatim) ----
    __syncthreads();
    #pragma unroll
    for (int q = 0; q < Q; ++q) {
        const int base = (g * Q + q) * KROW + s * K;
        kbuf[base + 0] = k0[q];
        kbuf[base + 1] = k1[q];
        kbuf[base + 2] = k2[q];
    }
    __syncthreads();

    // ---- merge stage A: 16 threads/query, each folds 12 keys -> top-4 -----
    {
        const int lp = t >> 4;           // local query 0..31
        const int ch = t & 15;           // chunk 0..15
        unsigned m0 = NOKEY, m1 = NOKEY, m2 = NOKEY, m3 = NOKEY;
        const unsigned* rowp = kbuf + lp * KROW + ch * 12;
        #pragma unroll
        for (int c = 0; c < 12; ++c) {
            const unsigned cc = rowp[c];
            m3 = med3u(m2, m3, cc);
            m2 = med3u(m1, m2, cc);
            m1 = med3u(m0, m1, cc);
            m0 = min(m0, cc);
        }
        unsigned* o = kbuf + KB2 + (lp * 16 + ch) * KA;
        o[0] = m0; o[1] = m1; o[2] = m2; o[3] = m3;
    }
    __syncthreads();

    // ---- merge stage B + exact-f64 re-rank + f64 IDW (t < 32) -------------
    if (t < PPB) {
        unsigned bk[KM];
        #pragma unroll
        for (int k = 0; k < KM; ++k) bk[k] = NOKEY;
        const unsigned* inp = kbuf + KB2 + t * 16 * KA;
        #pragma unroll
        for (int c = 0; c < 16 * KA; ++c) {
            const unsigned cc = inp[c];
            bk[7] = med3u(bk[6], bk[7], cc);
            bk[6] = med3u(bk[5], bk[6], cc);
            bk[5] = med3u(bk[4], bk[5], cc);
            bk[4] = med3u(bk[3], bk[4], cc);
            bk[3] = med3u(bk[2], bk[3], cc);
            bk[2] = med3u(bk[1], bk[2], cc);
            bk[1] = med3u(bk[0], bk[1], cc);
            bk[0] = min(bk[0], cc);
        }

        const unsigned qq = dsrt[chk * PPB + t];
        const double qxd = (double)xb[qq];
        const double qyd = (double)xb[NQ + qq];
        const double qzd = (double)xb[2 * NQ + qq];

        double e0 = 1e300, e1 = 1e300, e2 = 1e300;
        int    i0 = 0,     i1 = 0,     i2 = 0;
        #pragma unroll
        for (int c = 0; c < KM; ++c) {
            const unsigned key = bk[c];
            if (key == NOKEY) continue;
            const int j = (int)(key & 0xFFFu);
            const float4 p = ssrt[j];            // global, L2-hot
            const double dx = qxd - (double)p.x;
            const double dy = qyd - (double)p.y;
            const double dz = qzd - (double)p.z;
            const double d2 = dx * dx + dy * dy + dz * dz;
            if (d2 < e2) {
                if (d2 < e1) {
                    e2 = e1; i2 = i1;
                    if (d2 < e0) { e1 = e0; i1 = i0; e0 = d2; i0 = j; }
                    else         { e1 = d2; i1 = j; }
                } else {
                    e2 = d2; i2 = j;
                }
            }
        }

        double dist0 = sqrt(e0); dist0 = dist0 > 1e-10 ? dist0 : 1e-10;
        double dist1 = sqrt(e1); dist1 = dist1 > 1e-10 ? dist1 : 1e-10;
        double dist2 = sqrt(e2); dist2 = dist2 > 1e-10 ? dist2 : 1e-10;
        const double inv0 = 1.0 / dist0;
        const double inv1 = 1.0 / dist1;
        const double inv2 = 1.0 / dist2;
        const double wsum = inv0 + inv1 + inv2;

        const int so0 = (int)sidxg[i0];
        const int so1 = (int)sidxg[i1];
        const int so2 = (int)sidxg[i2];

        const float* fb = sflow + (size_t)b * 3 * S;
        float*       ob = out   + (size_t)b * 3 * NQ;
        #pragma unroll
        for (int c = 0; c < 3; ++c) {
            const float* fc = fb + c * S;
            const double o =
                (inv0 * (double)fc[so0] +
                 inv1 * (double)fc[so1] +
                 inv2 * (double)fc[so2]) / wsum;
            ob[c * NQ + qq] = (float)o;
        }
    }
}

extern "C" void kernel_launch(void* const* d_in, const int* in_sizes, int n_in,
                              void* d_out, int out_size, void* d_ws, size_t ws_size,
                              hipStream_t stream)
{
    const float* xyz  = (const float*)d_in[0];
    const float* sxyz = (const float*)d_in[1];
    const float* sflw = (const float*)d_in[2];
    float*       out  = (float*)d_out;
    unsigned*    ws32 = (unsigned*)d_ws;      // needs ~297 KB

    k_sort<<<4, 1024, 0, stream>>>(xyz, sxyz, ws32);
    k_knn<<<dim3(NQ / PPB, B), THREADS, 0, stream>>>(xyz, sflw, out, ws32);
}

// Round 18
// 39.566 us; speedup vs baseline: 2.4306x; 1.5741x over previous
//
#include <hip/hip_runtime.h>

// 3-NN IDW upsampling, FINAL (round-12 kernel, best measured: 39.5 us).
// Dense brute-force scan in the proven wave-uniform shape:
//  - 512-thread blocks, __launch_bounds__(512,4), grid 512 = 2 blocks/CU.
//  - AoS float4 {x,y,z,|p|^2} in LDS: ONE ds_read_b128 per point, and
//    dot-form distance v2 = (qq+1e-3) - 2 q.p + pp = 3 FMA + 1 add.
//    Bias 1e-3 >> fp32 error keeps keys positive/u32-monotone.
//  - Per-lane top-3 truncated packed keys via med3 sorted insert (1 op/level).
//  - Merge: 64 splits x top-3 -> 8 chunks x top-5-of-24 -> 40 -> top-8 ->
//    exact-f64 re-rank + f64 IDW epilogue (passed r1-r13, absmax 0.00390625).
// Rationale: 7 grid/window pruning variants (r5-r11, r14-r17) all lost to
// this dense scan on MI355X -- pair-count savings were eaten by staging,
// merge, and window-glue overhead. This config ties the occupancy-doubled
// r13 at 39.5 us: a robust structural plateau (~60% VALU issue on a 15.7 us
// theoretical pair floor + ~6 us glue).

constexpr int S_SPARSE = 4096;
constexpr int NSPLIT   = 64;                 // lane split of S per query
constexpr int Q        = 8;                  // queries per thread
constexpr int THREADS  = 512;                // 8 waves
constexpr int PPB      = 64;                 // queries per block (8 waves x 8)
constexpr int NITER    = S_SPARSE / NSPLIT;  // 64 scan iters per lane
constexpr int K        = 3;                  // per-split top-K kept
constexpr int KA       = 5;                  // stage-A top-K per 24-key chunk
constexpr int KM       = 8;                  // final candidates for f64 re-rank
constexpr int KROW     = NSPLIT * K + 8;     // 200 dwords
constexpr int KBUF2_OFF_DW = PPB * KROW;     // 12800 dwords
constexpr int PQ_PAD   = 64;                 // prefetch overrun guard

__device__ __forceinline__ unsigned med3u(unsigned a, unsigned b, unsigned c) {
    unsigned d;
    asm("v_med3_u32 %0, %1, %2, %3" : "=v"(d) : "v"(a), "v"(b), "v"(c));
    return d;
}

__global__ __launch_bounds__(THREADS, 4)
void upsample_knn3(const float* __restrict__ xyz,
                   const float* __restrict__ sxyz,
                   const float* __restrict__ sflow,
                   float* __restrict__ out,
                   int N)
{
    // 65 KiB: AoS float4 sparse points during scan; aliased as key-exchange
    // buffers afterwards (epilogue re-reads coords from global/L2).
    __shared__ __align__(16) unsigned char smem_raw[(S_SPARSE + PQ_PAD) * 16];
    float4*   pq   = reinterpret_cast<float4*>(smem_raw);
    unsigned* kbuf = reinterpret_cast<unsigned*>(smem_raw);

    const int t   = threadIdx.x;
    const int s   = t & 63;                  // lane = split
    const int g   = t >> 6;                  // wave = query group 0..7
    const int b   = blockIdx.y;
    const int chk = blockIdx.x;              // 0..255

    // ---- stage sparse points as AoS {x,y,z,|p|^2} ----
    const float* sx = sxyz + (size_t)b * 3 * S_SPARSE;
    const float* sy = sx + S_SPARSE;
    const float* sz = sy + S_SPARSE;
    #pragma unroll
    for (int it = 0; it < S_SPARSE / (THREADS * 4); ++it) {      // 2 iters
        const int j0 = (t + it * THREADS) * 4;
        const float4 vx = *reinterpret_cast<const float4*>(sx + j0);
        const float4 vy = *reinterpret_cast<const float4*>(sy + j0);
        const float4 vz = *reinterpret_cast<const float4*>(sz + j0);
        #pragma unroll
        for (int e = 0; e < 4; ++e) {
            const float px = (&vx.x)[e], py = (&vy.x)[e], pz = (&vz.x)[e];
            const float pp = fmaf(pz, pz, fmaf(py, py, px * px));
            pq[j0 + e] = make_float4(px, py, pz, pp);
        }
    }

    // ---- my 8 query points: precompute -2q and qq + bias ----
    const float* xb = xyz + (size_t)b * 3 * N;
    const int p0 = chk * PPB + g * Q;
    float m2x[Q], m2y[Q], m2z[Q], qqc[Q];
    {
        const float4 x0 = *reinterpret_cast<const float4*>(xb + p0);
        const float4 x1 = *reinterpret_cast<const float4*>(xb + p0 + 4);
        const float4 y0 = *reinterpret_cast<const float4*>(xb + N + p0);
        const float4 y1 = *reinterpret_cast<const float4*>(xb + N + p0 + 4);
        const float4 z0 = *reinterpret_cast<const float4*>(xb + 2 * N + p0);
        const float4 z1 = *reinterpret_cast<const float4*>(xb + 2 * N + p0 + 4);
        #pragma unroll
        for (int q = 0; q < Q; ++q) {
            const float qx = (q < 4) ? (&x0.x)[q] : (&x1.x)[q - 4];
            const float qy = (q < 4) ? (&y0.x)[q] : (&y1.x)[q - 4];
            const float qz = (q < 4) ? (&z0.x)[q] : (&z1.x)[q - 4];
            m2x[q] = -2.0f * qx;
            m2y[q] = -2.0f * qy;
            m2z[q] = -2.0f * qz;
            qqc[q] = fmaf(qz, qz, fmaf(qy, qy, qx * qx)) + 1e-3f;
        }
    }
    __syncthreads();

    // ---- scan: 1 ds_read_b128/point, 8 ops/pair, top-3 med3 insert ----
    unsigned k0[Q], k1[Q], k2[Q];
    #pragma unroll
    for (int q = 0; q < Q; ++q) { k0[q]=0xFFFFFFFFu; k1[q]=0xFFFFFFFFu; k2[q]=0xFFFFFFFFu; }

    float4 cur = pq[s];
    #pragma unroll 2
    for (int i = 0; i < NITER; ++i) {
        const int j = (i << 6) | s;
        const float4 nxt = pq[j + 64];       // last-iter prefetch lands in pad
        #pragma unroll
        for (int q = 0; q < Q; ++q) {
            const float v  = fmaf(m2x[q], cur.x,
                             fmaf(m2y[q], cur.y,
                             fmaf(m2z[q], cur.z, qqc[q])));
            const float v2 = v + cur.w;      // = d2 + 1e-3 (+-5e-6), > 0
            const unsigned c = (__float_as_uint(v2) & 0xFFFFF000u) | (unsigned)j;
            k2[q] = med3u(k1[q], k2[q], c);
            k1[q] = med3u(k0[q], k1[q], c);
            k0[q] = min(k0[q], c);
        }
        cur = nxt;
    }

    // ---- publish per-split sorted-3 lists (alias over pq) ----
    __syncthreads();
    #pragma unroll
    for (int q = 0; q < Q; ++q) {
        const int base = (g * Q + q) * KROW + s * K;
        kbuf[base + 0] = k0[q];
        kbuf[base + 1] = k1[q];
        kbuf[base + 2] = k2[q];
    }
    __syncthreads();

    // ---- merge stage A: 8 threads/query, each folds 24 keys -> top-5 ----
    {
        const int lp = t >> 3;               // local query 0..63
        const int ch = t & 7;                // chunk 0..7
        unsigned m0=0xFFFFFFFFu, m1=0xFFFFFFFFu, m2=0xFFFFFFFFu,
                 m3=0xFFFFFFFFu, m4=0xFFFFFFFFu;
        const unsigned* rowp = kbuf + lp * KROW + ch * 24;
        #pragma unroll
        for (int c = 0; c < 24; ++c) {
            const unsigned cc = rowp[c];
            m4 = med3u(m3, m4, cc);
            m3 = med3u(m2, m3, cc);
            m2 = med3u(m1, m2, cc);
            m1 = med3u(m0, m1, cc);
            m0 = min(m0, cc);
        }
        unsigned* o = kbuf + KBUF2_OFF_DW + (lp * 8 + ch) * KA;
        o[0]=m0; o[1]=m1; o[2]=m2; o[3]=m3; o[4]=m4;
    }
    __syncthreads();

    // ---- merge stage B + exact-f64 re-rank + f64 IDW (t < 64) ----
    if (t < PPB) {
        unsigned bk[KM];
        #pragma unroll
        for (int k = 0; k < KM; ++k) bk[k] = 0xFFFFFFFFu;
        const unsigned* inp = kbuf + KBUF2_OFF_DW + t * 8 * KA;
        #pragma unroll
        for (int c = 0; c < 8 * KA; ++c) {
            const unsigned cc = inp[c];
            bk[7] = med3u(bk[6], bk[7], cc);
            bk[6] = med3u(bk[5], bk[6], cc);
            bk[5] = med3u(bk[4], bk[5], cc);
            bk[4] = med3u(bk[3], bk[4], cc);
            bk[3] = med3u(bk[2], bk[3], cc);
            bk[2] = med3u(bk[1], bk[2], cc);
            bk[1] = med3u(bk[0], bk[1], cc);
            bk[0] = min(bk[0], cc);
        }

        // exact-f64 re-rank of 8 candidates (identical to rounds 1-13)
        const int pt = chk * PPB + t;
        const double qxd = (double)xb[pt];
        const double qyd = (double)xb[N + pt];
        const double qzd = (double)xb[2 * N + pt];

        double e0 = 1e300, e1 = 1e300, e2 = 1e300;
        int    j0 = 0,     j1 = 0,     j2 = 0;
        #pragma unroll
        for (int c = 0; c < KM; ++c) {
            const int    j  = (int)(bk[c] & 0xFFFu);
            const double dx = qxd - (double)sx[j];
            const double dy = qyd - (double)sy[j];
            const double dz = qzd - (double)sz[j];
            const double d2 = dx * dx + dy * dy + dz * dz;
            if (d2 < e2) {
                if (d2 < e1) {
                    e2 = e1; j2 = j1;
                    if (d2 < e0) { e1 = e0; j1 = j0; e0 = d2; j0 = j; }
                    else         { e1 = d2; j1 = j; }
                } else {
                    e2 = d2; j2 = j;
                }
            }
        }

        double dist0 = sqrt(e0); dist0 = dist0 > 1e-10 ? dist0 : 1e-10;
        double dist1 = sqrt(e1); dist1 = dist1 > 1e-10 ? dist1 : 1e-10;
        double dist2 = sqrt(e2); dist2 = dist2 > 1e-10 ? dist2 : 1e-10;
        const double inv0 = 1.0 / dist0;
        const double inv1 = 1.0 / dist1;
        const double inv2 = 1.0 / dist2;
        const double wsum = inv0 + inv1 + inv2;

        const float* fb = sflow + (size_t)b * 3 * S_SPARSE;
        float*       ob = out   + (size_t)b * 3 * N;
        #pragma unroll
        for (int c = 0; c < 3; ++c) {
            const float* fc = fb + c * S_SPARSE;
            const double o =
                (inv0 * (double)fc[j0] +
                 inv1 * (double)fc[j1] +
                 inv2 * (double)fc[j2]) / wsum;
            ob[c * N + pt] = (float)o;
        }
    }
}

extern "C" void kernel_launch(void* const* d_in, const int* in_sizes, int n_in,
                              void* d_out, int out_size, void* d_ws, size_t ws_size,
                              hipStream_t stream)
{
    const float* xyz  = (const float*)d_in[0];
    const float* sxyz = (const float*)d_in[1];
    const float* sflw = (const float*)d_in[2];
    float*       out  = (float*)d_out;

    const int B = 2;
    const int N = in_sizes[0] / (3 * B);     // 16384

    dim3 grid(N / PPB, B);                   // 256 x 2 = 512 blocks, 2/CU
    upsample_knn3<<<grid, THREADS, 0, stream>>>(xyz, sxyz, sflw, out, N);
}